// Round 2
// baseline (430.710 us; speedup 1.0000x reference)
//
#include <hip/hip_runtime.h>

#define N_NODES 50000
#define N_EDGES 800000
#define CH      128
#define TILE_R  64

typedef unsigned short u16;
typedef unsigned int   u32;
typedef __bf16 bf16x8 __attribute__((ext_vector_type(8)));
typedef float  f32x4  __attribute__((ext_vector_type(4)));

__device__ __forceinline__ float bf_lo(u32 v){ return __uint_as_float(v << 16); }
__device__ __forceinline__ float bf_hi(u32 v){ return __uint_as_float(v & 0xffff0000u); }
__device__ __forceinline__ u32 bf_pack(float a, float b){
    u32 ua = __float_as_uint(a), ub = __float_as_uint(b);
    ua += 0x7fffu + ((ua >> 16) & 1u);
    ub += 0x7fffu + ((ub >> 16) & 1u);
    return (ua >> 16) | (ub & 0xffff0000u);
}
__device__ __forceinline__ u16 f2bf(float a){
    u32 ua = __float_as_uint(a);
    ua += 0x7fffu + ((ua >> 16) & 1u);
    return (u16)(ua >> 16);
}

// ---- fp32 -> packed bf16 (2 per u32) --------------------------------------
__global__ void tobf16_kernel(const float* __restrict__ in, u32* __restrict__ out, int n2) {
    int i = blockIdx.x * 256 + threadIdx.x;
    if (i < n2) {
        float2 v = ((const float2*)in)[i];
        out[i] = bf_pack(v.x, v.y);
    }
}

// ---- prep: transpose W1a/W1b/W2a (fp32 [in][out]) -> bf16 [out][in];
//      fold Wc = W2b@Wfc (fp32), bc = b2b@Wfc + bfc (fp32)
__global__ void prep_kernel(const float* __restrict__ W1a, const float* __restrict__ W1b,
                            const float* __restrict__ W2a, const float* __restrict__ W2b,
                            const float* __restrict__ Wfc, const float* __restrict__ b2b,
                            const float* __restrict__ bfc,
                            u16* __restrict__ wt1a, u16* __restrict__ wt1b,
                            u16* __restrict__ wt2a,
                            float* __restrict__ Wc, float* __restrict__ bc) {
    int b = blockIdx.x, t = threadIdx.x;
    if (b < 192) {                       // 192*256 = 3*16384 transposed elements
        int g  = b * 256 + t;
        int mi = g >> 14;
        int p  = g & 16383;
        int k  = p >> 7, m = p & 127;    // source [k][m] (fan_in x fan_out)
        const float* src = (mi == 0) ? W1a : (mi == 1) ? W1b : W2a;
        u16* dst         = (mi == 0) ? wt1a : (mi == 1) ? wt1b : wt2a;
        dst[m * 128 + k] = f2bf(src[k * 128 + m]);
    } else {                             // b == 192: Wc[j][o], bc[o], all fp32
        int j = t >> 1, o = t & 1;
        float s = 0.f;
        for (int k = 0; k < 128; k++)
            s += W2b[j * 128 + k] * Wfc[k * 2 + o];
        Wc[j * 2 + o] = s;
        if (t < 2) {
            float s2 = 0.f;
            for (int k = 0; k < 128; k++)
                s2 += b2b[k] * Wfc[k * 2 + t];
            bc[t] = s2 + bfc[t];
        }
    }
}

// ---- CSR build -------------------------------------------------------------
__global__ void hist_kernel(const int* __restrict__ dst, int* __restrict__ deg, int e) {
    int i = blockIdx.x * 256 + threadIdx.x;
    if (i < e) atomicAdd(&deg[dst[i]], 1);
}

__global__ void scan_kernel(const int* __restrict__ deg, int* __restrict__ offs,
                            int* __restrict__ cursor) {
    __shared__ int sums[1024];
    const int n = N_NODES, T = 1024, C = (N_NODES + 1023) / 1024;
    int t = threadIdx.x;
    int start = t * C, end = min(start + C, n);
    int s = 0;
    for (int i = start; i < end; i++) s += deg[i];
    sums[t] = s;
    __syncthreads();
    for (int off = 1; off < T; off <<= 1) {
        int v = (t >= off) ? sums[t - off] : 0;
        __syncthreads();
        sums[t] += v;
        __syncthreads();
    }
    int base = sums[t] - s;              // exclusive prefix for this chunk
    for (int i = start; i < end; i++) {
        offs[i] = base;
        cursor[i] = base;
        base += deg[i];
    }
    if (t == T - 1) offs[n] = sums[T - 1];
}

__global__ void fill_kernel(const int* __restrict__ src, const int* __restrict__ dst,
                            int* __restrict__ cursor, int* __restrict__ csr, int e) {
    int i = blockIdx.x * 256 + threadIdx.x;
    if (i < e) {
        int p = atomicAdd(&cursor[dst[i]], 1);
        csr[p] = src[i];
    }
}

// ---- aggregation: out[i] = x[i] + sum_{j in N(i)} x[j]  (packed bf16, fp32 acc)
// one wave per node, lane holds 2 channels packed in a dword
__global__ void agg_kernel(const u32* __restrict__ x, u32* __restrict__ out,
                           const int* __restrict__ offs, const int* __restrict__ csr) {
    int wid  = (blockIdx.x * blockDim.x + threadIdx.x) >> 6;
    int lane = threadIdx.x & 63;
    if (wid >= N_NODES) return;
    int j = offs[wid], jend = offs[wid + 1];
    u32 v = x[wid * 64 + lane];
    float a0 = bf_lo(v), a1 = bf_hi(v);
    for (; j + 4 <= jend; j += 4) {
        int s0 = csr[j], s1 = csr[j + 1], s2 = csr[j + 2], s3 = csr[j + 3];
        u32 w0 = x[s0 * 64 + lane], w1 = x[s1 * 64 + lane];
        u32 w2 = x[s2 * 64 + lane], w3 = x[s3 * 64 + lane];
        a0 += bf_lo(w0) + bf_lo(w1) + bf_lo(w2) + bf_lo(w3);
        a1 += bf_hi(w0) + bf_hi(w1) + bf_hi(w2) + bf_hi(w3);
    }
    for (; j < jend; j++) {
        u32 w = x[csr[j] * 64 + lane];
        a0 += bf_lo(w); a1 += bf_hi(w);
    }
    out[wid * 64 + lane] = bf_pack(a0, a1);
}

// ---- GEMM: C[n,128] = relu(A[n,128] @ W[128,128] + b), bf16 in/out, fp32 bias
// Wt is W transposed: [out m][in k]. LDS stride padded to 136 (2-way conflict = free).
__launch_bounds__(256)
__global__ void gemm_relu_kernel(const u16* __restrict__ A, const u16* __restrict__ Wt,
                                 const float* __restrict__ bias, u16* __restrict__ C,
                                 int n) {
    __shared__ u16 Ws[128][136];
    __shared__ u16 As[TILE_R][136];
    int t = threadIdx.x;
    {   // stage W: 128x128 bf16, thread t -> row t>>1, half t&1 (8 x uint4)
        int r = t >> 1, p = t & 1;
        const uint4* s = (const uint4*)(Wt + r * 128 + p * 64);
        uint4* d = (uint4*)&Ws[r][p * 64];
        #pragma unroll
        for (int i = 0; i < 8; i++) d[i] = s[i];
    }
    int row0 = blockIdx.x * TILE_R;
    {   // stage A tile: 64 rows, thread t -> row t>>2, quarter t&3 (4 x uint4)
        int r = t >> 2, p = t & 3;
        int g = row0 + r;
        const uint4* s = (const uint4*)(A + (size_t)g * 128 + p * 32);
        uint4* d = (uint4*)&As[r][p * 32];
        #pragma unroll
        for (int i = 0; i < 4; i++) {
            uint4 v = make_uint4(0, 0, 0, 0);
            if (g < n) v = s[i];
            d[i] = v;
        }
    }
    __syncthreads();

    int w = t >> 6, lane = t & 63;
    int lm = lane & 15, lq = lane >> 4;
    f32x4 acc[8];
    #pragma unroll
    for (int c = 0; c < 8; c++) acc[c] = (f32x4){0.f, 0.f, 0.f, 0.f};
    #pragma unroll
    for (int kk = 0; kk < 4; kk++) {
        bf16x8 af = *(const bf16x8*)&As[w * 16 + lm][kk * 32 + lq * 8];
        #pragma unroll
        for (int c = 0; c < 8; c++) {
            bf16x8 bf = *(const bf16x8*)&Ws[c * 16 + lm][kk * 32 + lq * 8];
            acc[c] = __builtin_amdgcn_mfma_f32_16x16x32_bf16(af, bf, acc[c], 0, 0, 0);
        }
    }
    // epilogue: C/D layout col=lane&15, row=(lane>>4)*4+reg
    #pragma unroll
    for (int c = 0; c < 8; c++) {
        #pragma unroll
        for (int r = 0; r < 4; r++) {
            int row = row0 + w * 16 + lq * 4 + r;
            int col = c * 16 + lm;
            if (row < n) {
                float v = acc[c][r] + bias[col];
                v = v > 0.f ? v : 0.f;
                C[(size_t)row * 128 + col] = f2bf(v);
            }
        }
    }
}

// ---- final FC: out[n,2] = t2[n,128] @ Wc[128,2] + bc ; wave per node; fp32 out
__global__ void fc_kernel(const u32* __restrict__ T2, const float* __restrict__ Wc,
                          const float* __restrict__ bc, float2* __restrict__ out) {
    int wid  = (blockIdx.x * blockDim.x + threadIdx.x) >> 6;
    int lane = threadIdx.x & 63;
    if (wid >= N_NODES) return;
    u32 v = T2[wid * 64 + lane];
    float f0 = bf_lo(v), f1 = bf_hi(v);
    float4 wv = ((const float4*)Wc)[lane];   // Wc[2l][0..1], Wc[2l+1][0..1]
    float p0 = f0 * wv.x + f1 * wv.z;
    float p1 = f0 * wv.y + f1 * wv.w;
    #pragma unroll
    for (int off = 32; off; off >>= 1) {
        p0 += __shfl_xor(p0, off);
        p1 += __shfl_xor(p1, off);
    }
    if (lane == 0) out[wid] = make_float2(p0 + bc[0], p1 + bc[1]);
}

extern "C" void kernel_launch(void* const* d_in, const int* in_sizes, int n_in,
                              void* d_out, int out_size, void* d_ws, size_t ws_size,
                              hipStream_t stream) {
    const float* x   = (const float*)d_in[0];
    const int*   ei  = (const int*)d_in[1];
    const float* W1a = (const float*)d_in[2];
    const float* b1a = (const float*)d_in[3];
    const float* W1b = (const float*)d_in[4];
    const float* b1b = (const float*)d_in[5];
    const float* W2a = (const float*)d_in[6];
    const float* b2a = (const float*)d_in[7];
    const float* W2b = (const float*)d_in[8];
    const float* b2b = (const float*)d_in[9];
    const float* Wfc = (const float*)d_in[10];
    const float* bfc = (const float*)d_in[11];

    const int* esrc = ei;
    const int* edst = ei + N_EDGES;

    char* w = (char*)d_ws;
    size_t off = 0;
    auto alloc = [&](size_t bytes) -> char* {
        char* p = w + off;
        off = (off + bytes + 255) & ~(size_t)255;
        return p;
    };
    int* deg     = (int*)alloc(N_NODES * 4);
    int* offs    = (int*)alloc((N_NODES + 1) * 4);
    int* cursor  = (int*)alloc(N_NODES * 4);
    int* csr     = (int*)alloc((size_t)N_EDGES * 4);
    u16* wt1a    = (u16*)alloc(128 * 128 * 2);
    u16* wt1b    = (u16*)alloc(128 * 128 * 2);
    u16* wt2a    = (u16*)alloc(128 * 128 * 2);
    float* Wc    = (float*)alloc(256 * 4);
    float* bc    = (float*)alloc(2 * 4);
    u16* bufA    = (u16*)alloc((size_t)N_NODES * 128 * 2);
    u16* bufB    = (u16*)alloc((size_t)N_NODES * 128 * 2);

    hipMemsetAsync(deg, 0, N_NODES * 4, stream);
    prep_kernel<<<193, 256, 0, stream>>>(W1a, W1b, W2a, W2b, Wfc, b2b, bfc,
                                         wt1a, wt1b, wt2a, Wc, bc);
    const int EB = (N_EDGES + 255) / 256;
    hist_kernel<<<EB, 256, 0, stream>>>(edst, deg, N_EDGES);
    scan_kernel<<<1, 1024, 0, stream>>>(deg, offs, cursor);
    fill_kernel<<<EB, 256, 0, stream>>>(esrc, edst, cursor, csr, N_EDGES);

    const int AGG_B = (N_NODES + 3) / 4;         // 4 waves per 256-block
    const int TILES = (N_NODES + TILE_R - 1) / TILE_R;
    const int CVT_B = (N_NODES * 64 + 255) / 256;

    // x (fp32) -> bufB (packed bf16)
    tobf16_kernel<<<CVT_B, 256, 0, stream>>>(x, (u32*)bufB, N_NODES * 64);
    // conv1: agg -> bufA ; gemm(W1a)+relu -> bufB ; gemm(W1b)+outer relu -> bufA (=h1)
    agg_kernel<<<AGG_B, 256, 0, stream>>>((const u32*)bufB, (u32*)bufA, offs, csr);
    gemm_relu_kernel<<<TILES, 256, 0, stream>>>(bufA, wt1a, b1a, bufB, N_NODES);
    gemm_relu_kernel<<<TILES, 256, 0, stream>>>(bufB, wt1b, b1b, bufA, N_NODES);
    // conv2: agg(h1) -> bufB ; gemm(W2a)+relu -> bufA (=t2)
    agg_kernel<<<AGG_B, 256, 0, stream>>>((const u32*)bufA, (u32*)bufB, offs, csr);
    gemm_relu_kernel<<<TILES, 256, 0, stream>>>(bufB, wt2a, b2a, bufA, N_NODES);
    // fc: t2 @ (W2b@Wfc) + (b2b@Wfc + bfc) -> d_out (fp32)
    fc_kernel<<<AGG_B, 256, 0, stream>>>((const u32*)bufA, Wc, bc, (float2*)d_out);
}

// Round 3
// 321.689 us; speedup vs baseline: 1.3389x; 1.3389x over previous
//
#include <hip/hip_runtime.h>

#define N_NODES 50000
#define N_EDGES 800000
#define CH      128
#define TILE_R  64
#define NB      196          // ceil(N_NODES / 256)

typedef unsigned short u16;
typedef unsigned int   u32;
typedef __bf16 bf16x8 __attribute__((ext_vector_type(8)));
typedef float  f32x4  __attribute__((ext_vector_type(4)));

__device__ __forceinline__ float bf_lo(u32 v){ return __uint_as_float(v << 16); }
__device__ __forceinline__ float bf_hi(u32 v){ return __uint_as_float(v & 0xffff0000u); }
__device__ __forceinline__ u32 bf_pack(float a, float b){
    u32 ua = __float_as_uint(a), ub = __float_as_uint(b);
    ua += 0x7fffu + ((ua >> 16) & 1u);
    ub += 0x7fffu + ((ub >> 16) & 1u);
    return (ua >> 16) | (ub & 0xffff0000u);
}
__device__ __forceinline__ u16 f2bf(float a){
    u32 ua = __float_as_uint(a);
    ua += 0x7fffu + ((ua >> 16) & 1u);
    return (u16)(ua >> 16);
}

// ---- fp32 -> packed bf16 (2 per u32) --------------------------------------
__global__ void tobf16_kernel(const float* __restrict__ in, u32* __restrict__ out, int n2) {
    int i = blockIdx.x * 256 + threadIdx.x;
    if (i < n2) {
        float2 v = ((const float2*)in)[i];
        out[i] = bf_pack(v.x, v.y);
    }
}

// ---- prep: transpose W1a/W1b/W2a (fp32 [in][out]) -> bf16 [out][in];
//      fold Wc = W2b@Wfc (fp32), bc = b2b@Wfc + bfc (fp32)
__global__ void prep_kernel(const float* __restrict__ W1a, const float* __restrict__ W1b,
                            const float* __restrict__ W2a, const float* __restrict__ W2b,
                            const float* __restrict__ Wfc, const float* __restrict__ b2b,
                            const float* __restrict__ bfc,
                            u16* __restrict__ wt1a, u16* __restrict__ wt1b,
                            u16* __restrict__ wt2a,
                            float* __restrict__ Wc, float* __restrict__ bc) {
    int b = blockIdx.x, t = threadIdx.x;
    if (b < 192) {                       // 192*256 = 3*16384 transposed elements
        int g  = b * 256 + t;
        int mi = g >> 14;
        int p  = g & 16383;
        int k  = p >> 7, m = p & 127;    // source [k][m] (fan_in x fan_out)
        const float* src = (mi == 0) ? W1a : (mi == 1) ? W1b : W2a;
        u16* dst         = (mi == 0) ? wt1a : (mi == 1) ? wt1b : wt2a;
        dst[m * 128 + k] = f2bf(src[k * 128 + m]);
    } else {                             // b == 192: Wc[j][o], bc[o], all fp32
        int j = t >> 1, o = t & 1;
        float s = 0.f;
        for (int k = 0; k < 128; k++)
            s += W2b[j * 128 + k] * Wfc[k * 2 + o];
        Wc[j * 2 + o] = s;
        if (t < 2) {
            float s2 = 0.f;
            for (int k = 0; k < 128; k++)
                s2 += b2b[k] * Wfc[k * 2 + t];
            bc[t] = s2 + bfc[t];
        }
    }
}

// ---- CSR build -------------------------------------------------------------
__global__ void hist_kernel(const int* __restrict__ dst, int* __restrict__ deg, int e) {
    int i = blockIdx.x * 256 + threadIdx.x;
    if (i < e) atomicAdd(&deg[dst[i]], 1);
}

// two-level parallel scan: bsum (per-block reduce) -> pscan (scan partials)
// -> scatter (per-element exclusive prefix + block base)
__global__ void bsum_kernel(const int* __restrict__ deg, int* __restrict__ bsums) {
    int t = threadIdx.x, lane = t & 63, w = t >> 6;
    int i = blockIdx.x * 256 + t;
    int v = (i < N_NODES) ? deg[i] : 0;
    #pragma unroll
    for (int off = 32; off; off >>= 1) v += __shfl_xor(v, off);
    __shared__ int ws[4];
    if (lane == 0) ws[w] = v;
    __syncthreads();
    if (t == 0) bsums[blockIdx.x] = ws[0] + ws[1] + ws[2] + ws[3];
}

__global__ void pscan_kernel(const int* __restrict__ bsums, int* __restrict__ bbase,
                             int* __restrict__ offs) {
    int t = threadIdx.x, lane = t & 63, w = t >> 6;
    int s = (t < NB) ? bsums[t] : 0;
    int v = s;
    #pragma unroll
    for (int off = 1; off < 64; off <<= 1) {
        int u = __shfl_up(v, off);
        if (lane >= off) v += u;
    }
    __shared__ int ws[4];
    if (lane == 63) ws[w] = v;
    __syncthreads();
    int add = 0;
    for (int k = 0; k < w; k++) add += ws[k];
    v += add;
    if (t < NB) bbase[t] = v - s;        // exclusive base for block t
    if (t == NB - 1) offs[N_NODES] = v;  // total edge count
}

__global__ void scatter_kernel(const int* __restrict__ deg, const int* __restrict__ bbase,
                               int* __restrict__ offs, int* __restrict__ cursor) {
    int t = threadIdx.x, lane = t & 63, w = t >> 6;
    int i = blockIdx.x * 256 + t;
    int s = (i < N_NODES) ? deg[i] : 0;
    int v = s;
    #pragma unroll
    for (int off = 1; off < 64; off <<= 1) {
        int u = __shfl_up(v, off);
        if (lane >= off) v += u;
    }
    __shared__ int ws[4];
    if (lane == 63) ws[w] = v;
    __syncthreads();
    int add = bbase[blockIdx.x];
    for (int k = 0; k < w; k++) add += ws[k];
    int excl = add + v - s;
    if (i < N_NODES) {
        offs[i] = excl;
        cursor[i] = excl;
    }
}

__global__ void fill_kernel(const int* __restrict__ src, const int* __restrict__ dst,
                            int* __restrict__ cursor, int* __restrict__ csr, int e) {
    int i = blockIdx.x * 256 + threadIdx.x;
    if (i < e) {
        int p = atomicAdd(&cursor[dst[i]], 1);
        csr[p] = src[i];
    }
}

// ---- aggregation: out[i] = x[i] + sum_{j in N(i)} x[j]  (packed bf16, fp32 acc)
// one wave per node, lane holds 2 channels packed in a dword; 8-deep gather unroll
__global__ void agg_kernel(const u32* __restrict__ x, u32* __restrict__ out,
                           const int* __restrict__ offs, const int* __restrict__ csr) {
    int wid  = (blockIdx.x * blockDim.x + threadIdx.x) >> 6;
    int lane = threadIdx.x & 63;
    if (wid >= N_NODES) return;
    int j = offs[wid], jend = offs[wid + 1];
    u32 v = x[wid * 64 + lane];
    float a0 = bf_lo(v), a1 = bf_hi(v);
    for (; j + 8 <= jend; j += 8) {
        int s0 = csr[j],     s1 = csr[j + 1], s2 = csr[j + 2], s3 = csr[j + 3];
        int s4 = csr[j + 4], s5 = csr[j + 5], s6 = csr[j + 6], s7 = csr[j + 7];
        u32 w0 = x[s0 * 64 + lane], w1 = x[s1 * 64 + lane];
        u32 w2 = x[s2 * 64 + lane], w3 = x[s3 * 64 + lane];
        u32 w4 = x[s4 * 64 + lane], w5 = x[s5 * 64 + lane];
        u32 w6 = x[s6 * 64 + lane], w7 = x[s7 * 64 + lane];
        a0 += bf_lo(w0) + bf_lo(w1) + bf_lo(w2) + bf_lo(w3)
            + bf_lo(w4) + bf_lo(w5) + bf_lo(w6) + bf_lo(w7);
        a1 += bf_hi(w0) + bf_hi(w1) + bf_hi(w2) + bf_hi(w3)
            + bf_hi(w4) + bf_hi(w5) + bf_hi(w6) + bf_hi(w7);
    }
    for (; j + 4 <= jend; j += 4) {
        int s0 = csr[j], s1 = csr[j + 1], s2 = csr[j + 2], s3 = csr[j + 3];
        u32 w0 = x[s0 * 64 + lane], w1 = x[s1 * 64 + lane];
        u32 w2 = x[s2 * 64 + lane], w3 = x[s3 * 64 + lane];
        a0 += bf_lo(w0) + bf_lo(w1) + bf_lo(w2) + bf_lo(w3);
        a1 += bf_hi(w0) + bf_hi(w1) + bf_hi(w2) + bf_hi(w3);
    }
    for (; j < jend; j++) {
        u32 w = x[csr[j] * 64 + lane];
        a0 += bf_lo(w); a1 += bf_hi(w);
    }
    out[wid * 64 + lane] = bf_pack(a0, a1);
}

// ---- GEMM: C[n,128] = relu(A[n,128] @ W[128,128] + b), bf16 in/out, fp32 bias
// Wt is W transposed: [out m][in k]. LDS stride padded to 136 (2-way conflict = free).
__launch_bounds__(256)
__global__ void gemm_relu_kernel(const u16* __restrict__ A, const u16* __restrict__ Wt,
                                 const float* __restrict__ bias, u16* __restrict__ C,
                                 int n) {
    __shared__ u16 Ws[128][136];
    __shared__ u16 As[TILE_R][136];
    int t = threadIdx.x;
    {   // stage W: 128x128 bf16, thread t -> row t>>1, half t&1 (8 x uint4)
        int r = t >> 1, p = t & 1;
        const uint4* s = (const uint4*)(Wt + r * 128 + p * 64);
        uint4* d = (uint4*)&Ws[r][p * 64];
        #pragma unroll
        for (int i = 0; i < 8; i++) d[i] = s[i];
    }
    int row0 = blockIdx.x * TILE_R;
    {   // stage A tile: 64 rows, thread t -> row t>>2, quarter t&3 (4 x uint4)
        int r = t >> 2, p = t & 3;
        int g = row0 + r;
        const uint4* s = (const uint4*)(A + (size_t)g * 128 + p * 32);
        uint4* d = (uint4*)&As[r][p * 32];
        #pragma unroll
        for (int i = 0; i < 4; i++) {
            uint4 v = make_uint4(0, 0, 0, 0);
            if (g < n) v = s[i];
            d[i] = v;
        }
    }
    __syncthreads();

    int w = t >> 6, lane = t & 63;
    int lm = lane & 15, lq = lane >> 4;
    f32x4 acc[8];
    #pragma unroll
    for (int c = 0; c < 8; c++) acc[c] = (f32x4){0.f, 0.f, 0.f, 0.f};
    #pragma unroll
    for (int kk = 0; kk < 4; kk++) {
        bf16x8 af = *(const bf16x8*)&As[w * 16 + lm][kk * 32 + lq * 8];
        #pragma unroll
        for (int c = 0; c < 8; c++) {
            bf16x8 bf = *(const bf16x8*)&Ws[c * 16 + lm][kk * 32 + lq * 8];
            acc[c] = __builtin_amdgcn_mfma_f32_16x16x32_bf16(af, bf, acc[c], 0, 0, 0);
        }
    }
    // epilogue: C/D layout col=lane&15, row=(lane>>4)*4+reg
    #pragma unroll
    for (int c = 0; c < 8; c++) {
        #pragma unroll
        for (int r = 0; r < 4; r++) {
            int row = row0 + w * 16 + lq * 4 + r;
            int col = c * 16 + lm;
            if (row < n) {
                float v = acc[c][r] + bias[col];
                v = v > 0.f ? v : 0.f;
                C[(size_t)row * 128 + col] = f2bf(v);
            }
        }
    }
}

// ---- final FC: out[n,2] = t2[n,128] @ Wc[128,2] + bc ; wave per node; fp32 out
__global__ void fc_kernel(const u32* __restrict__ T2, const float* __restrict__ Wc,
                          const float* __restrict__ bc, float2* __restrict__ out) {
    int wid  = (blockIdx.x * blockDim.x + threadIdx.x) >> 6;
    int lane = threadIdx.x & 63;
    if (wid >= N_NODES) return;
    u32 v = T2[wid * 64 + lane];
    float f0 = bf_lo(v), f1 = bf_hi(v);
    float4 wv = ((const float4*)Wc)[lane];   // Wc[2l][0..1], Wc[2l+1][0..1]
    float p0 = f0 * wv.x + f1 * wv.z;
    float p1 = f0 * wv.y + f1 * wv.w;
    #pragma unroll
    for (int off = 32; off; off >>= 1) {
        p0 += __shfl_xor(p0, off);
        p1 += __shfl_xor(p1, off);
    }
    if (lane == 0) out[wid] = make_float2(p0 + bc[0], p1 + bc[1]);
}

extern "C" void kernel_launch(void* const* d_in, const int* in_sizes, int n_in,
                              void* d_out, int out_size, void* d_ws, size_t ws_size,
                              hipStream_t stream) {
    const float* x   = (const float*)d_in[0];
    const int*   ei  = (const int*)d_in[1];
    const float* W1a = (const float*)d_in[2];
    const float* b1a = (const float*)d_in[3];
    const float* W1b = (const float*)d_in[4];
    const float* b1b = (const float*)d_in[5];
    const float* W2a = (const float*)d_in[6];
    const float* b2a = (const float*)d_in[7];
    const float* W2b = (const float*)d_in[8];
    const float* b2b = (const float*)d_in[9];
    const float* Wfc = (const float*)d_in[10];
    const float* bfc = (const float*)d_in[11];

    const int* esrc = ei;
    const int* edst = ei + N_EDGES;

    char* w = (char*)d_ws;
    size_t off = 0;
    auto alloc = [&](size_t bytes) -> char* {
        char* p = w + off;
        off = (off + bytes + 255) & ~(size_t)255;
        return p;
    };
    int* deg     = (int*)alloc(N_NODES * 4);
    int* offs    = (int*)alloc((N_NODES + 1) * 4);
    int* cursor  = (int*)alloc(N_NODES * 4);
    int* bsums   = (int*)alloc(NB * 4);
    int* bbase   = (int*)alloc(NB * 4);
    int* csr     = (int*)alloc((size_t)N_EDGES * 4);
    u16* wt1a    = (u16*)alloc(128 * 128 * 2);
    u16* wt1b    = (u16*)alloc(128 * 128 * 2);
    u16* wt2a    = (u16*)alloc(128 * 128 * 2);
    float* Wc    = (float*)alloc(256 * 4);
    float* bc    = (float*)alloc(2 * 4);
    u16* bufA    = (u16*)alloc((size_t)N_NODES * 128 * 2);
    u16* bufB    = (u16*)alloc((size_t)N_NODES * 128 * 2);

    hipMemsetAsync(deg, 0, N_NODES * 4, stream);
    prep_kernel<<<193, 256, 0, stream>>>(W1a, W1b, W2a, W2b, Wfc, b2b, bfc,
                                         wt1a, wt1b, wt2a, Wc, bc);
    const int EB = (N_EDGES + 255) / 256;
    hist_kernel<<<EB, 256, 0, stream>>>(edst, deg, N_EDGES);
    bsum_kernel<<<NB, 256, 0, stream>>>(deg, bsums);
    pscan_kernel<<<1, 256, 0, stream>>>(bsums, bbase, offs);
    scatter_kernel<<<NB, 256, 0, stream>>>(deg, bbase, offs, cursor);
    fill_kernel<<<EB, 256, 0, stream>>>(esrc, edst, cursor, csr, N_EDGES);

    const int AGG_B = (N_NODES + 3) / 4;         // 4 waves per 256-block
    const int TILES = (N_NODES + TILE_R - 1) / TILE_R;
    const int CVT_B = (N_NODES * 64 + 255) / 256;

    // x (fp32) -> bufB (packed bf16)
    tobf16_kernel<<<CVT_B, 256, 0, stream>>>(x, (u32*)bufB, N_NODES * 64);
    // conv1: agg -> bufA ; gemm(W1a)+relu -> bufB ; gemm(W1b)+outer relu -> bufA (=h1)
    agg_kernel<<<AGG_B, 256, 0, stream>>>((const u32*)bufB, (u32*)bufA, offs, csr);
    gemm_relu_kernel<<<TILES, 256, 0, stream>>>(bufA, wt1a, b1a, bufB, N_NODES);
    gemm_relu_kernel<<<TILES, 256, 0, stream>>>(bufB, wt1b, b1b, bufA, N_NODES);
    // conv2: agg(h1) -> bufB ; gemm(W2a)+relu -> bufA (=t2)
    agg_kernel<<<AGG_B, 256, 0, stream>>>((const u32*)bufA, (u32*)bufB, offs, csr);
    gemm_relu_kernel<<<TILES, 256, 0, stream>>>(bufB, wt2a, b2a, bufA, N_NODES);
    // fc: t2 @ (W2b@Wfc) + (b2b@Wfc + bfc) -> d_out (fp32)
    fc_kernel<<<AGG_B, 256, 0, stream>>>((const u32*)bufA, Wc, bc, (float2*)d_out);
}

// Round 4
// 275.858 us; speedup vs baseline: 1.5614x; 1.1661x over previous
//
#include <hip/hip_runtime.h>

#define N_NODES 50000
#define N_EDGES 800000
#define CH      128
#define TILE_R  64
#define NBUK    196          // buckets of 256 nodes: dst>>8, max 49999>>8 = 195
#define B_A     128          // phase-A blocks
#define EPB     6250         // edges per phase-A block (128*6250 = 800000)
#define CAP     5120         // LDS capacity per bucket in phase B (mean 4096, 16 sigma margin)

typedef unsigned short u16;
typedef unsigned int   u32;
typedef unsigned long long u64;
typedef __bf16 bf16x8 __attribute__((ext_vector_type(8)));
typedef float  f32x4  __attribute__((ext_vector_type(4)));

__device__ __forceinline__ float bf_lo(u32 v){ return __uint_as_float(v << 16); }
__device__ __forceinline__ float bf_hi(u32 v){ return __uint_as_float(v & 0xffff0000u); }
__device__ __forceinline__ u32 bf_pack(float a, float b){
    u32 ua = __float_as_uint(a), ub = __float_as_uint(b);
    ua += 0x7fffu + ((ua >> 16) & 1u);
    ub += 0x7fffu + ((ub >> 16) & 1u);
    return (ua >> 16) | (ub & 0xffff0000u);
}
__device__ __forceinline__ u16 f2bf(float a){
    u32 ua = __float_as_uint(a);
    ua += 0x7fffu + ((ua >> 16) & 1u);
    return (u16)(ua >> 16);
}
__device__ __forceinline__ void addbf4(u64 w, float& a0, float& a1, float& a2, float& a3){
    u32 lo = (u32)w, hi = (u32)(w >> 32);
    a0 += bf_lo(lo); a1 += bf_hi(lo); a2 += bf_lo(hi); a3 += bf_hi(hi);
}

// inclusive block-scan of one int per thread (256 threads, 4 waves).
// Caller must __syncthreads() between the previous use of ws and this call.
__device__ __forceinline__ int blockScan256(int v, int* ws, int t) {
    int lane = t & 63, w = t >> 6;
    #pragma unroll
    for (int off = 1; off < 64; off <<= 1) {
        int u = __shfl_up(v, off);
        if (lane >= off) v += u;
    }
    if (lane == 63) ws[w] = v;
    __syncthreads();
    int add = 0;
    for (int k = 0; k < w; k++) add += ws[k];
    return v + add;
}

// ---- fp32 -> packed bf16 (2 per u32) --------------------------------------
__global__ void tobf16_kernel(const float* __restrict__ in, u32* __restrict__ out, int n2) {
    int i = blockIdx.x * 256 + threadIdx.x;
    if (i < n2) {
        float2 v = ((const float2*)in)[i];
        out[i] = bf_pack(v.x, v.y);
    }
}

// ---- prep: transpose W1a/W1b/W2a (fp32 [in][out]) -> bf16 [out][in];
//      fold Wc = W2b@Wfc (fp32), bc = b2b@Wfc + bfc (fp32)
__global__ void prep_kernel(const float* __restrict__ W1a, const float* __restrict__ W1b,
                            const float* __restrict__ W2a, const float* __restrict__ W2b,
                            const float* __restrict__ Wfc, const float* __restrict__ b2b,
                            const float* __restrict__ bfc,
                            u16* __restrict__ wt1a, u16* __restrict__ wt1b,
                            u16* __restrict__ wt2a,
                            float* __restrict__ Wc, float* __restrict__ bc) {
    int b = blockIdx.x, t = threadIdx.x;
    if (b < 192) {
        int g  = b * 256 + t;
        int mi = g >> 14;
        int p  = g & 16383;
        int k  = p >> 7, m = p & 127;
        const float* src = (mi == 0) ? W1a : (mi == 1) ? W1b : W2a;
        u16* dst         = (mi == 0) ? wt1a : (mi == 1) ? wt1b : wt2a;
        dst[m * 128 + k] = f2bf(src[k * 128 + m]);
    } else {
        int j = t >> 1, o = t & 1;
        float s = 0.f;
        for (int k = 0; k < 128; k++)
            s += W2b[j * 128 + k] * Wfc[k * 2 + o];
        Wc[j * 2 + o] = s;
        if (t < 2) {
            float s2 = 0.f;
            for (int k = 0; k < 128; k++)
                s2 += b2b[k] * Wfc[k * 2 + t];
            bc[t] = s2 + bfc[t];
        }
    }
}

// ---- CSR build: two-phase locality-staged counting sort --------------------
// Phase A: per-block sort of its 6250 edges into 196 coarse buckets (dst>>8),
// staged entirely in LDS, flushed linearly (no scattered global writes).
__launch_bounds__(256)
__global__ void binA_kernel(const int* __restrict__ esrc, const int* __restrict__ edst,
                            u32* __restrict__ binned, int* __restrict__ startTab,
                            int* __restrict__ cntTab) {
    __shared__ int hist[NBUK];
    __shared__ int cur[NBUK];
    __shared__ u32 ebuf[EPB];
    __shared__ int ws[4];
    int t = threadIdx.x, blk = blockIdx.x;
    int base = blk * EPB;
    for (int i = t; i < NBUK; i += 256) hist[i] = 0;
    __syncthreads();
    for (int i = t; i < EPB; i += 256)
        atomicAdd(&hist[edst[base + i] >> 8], 1);
    __syncthreads();
    int v = (t < NBUK) ? hist[t] : 0;
    int incl = blockScan256(v, ws, t);
    int excl = incl - v;
    if (t < NBUK) {
        startTab[blk * NBUK + t] = excl;
        cntTab[blk * NBUK + t]   = v;
        cur[t] = excl;
    }
    __syncthreads();
    for (int i = t; i < EPB; i += 256) {
        int d = edst[base + i], s = esrc[base + i];
        int p = atomicAdd(&cur[d >> 8], 1);
        ebuf[p] = (u32)s | ((u32)(d & 255) << 16);   // src(16b) | dst_local(8b)
    }
    __syncthreads();
    for (int i = t; i < EPB; i += 256)               // linear flush: full lines
        binned[base + i] = ebuf[i];
}

// bucket totals + exclusive scan (tiny)
__global__ void bscan_kernel(const int* __restrict__ cntTab, int* __restrict__ bucketBase,
                             int* __restrict__ offs) {
    __shared__ int ws[4];
    int t = threadIdx.x;
    int s = 0;
    if (t < NBUK) {
        #pragma unroll 8
        for (int blk = 0; blk < B_A; blk++) s += cntTab[blk * NBUK + t];
    }
    int incl = blockScan256(s, ws, t);
    if (t < NBUK) bucketBase[t] = incl - s;
    if (t == 0) offs[N_NODES] = N_EDGES;
}

// Phase B: one block per bucket (256 nodes). Gather the bucket's 128 runs to
// LDS, local histogram+scan, scatter in LDS, linear flush to csr; write offs.
__launch_bounds__(256)
__global__ void binB_kernel(const u32* __restrict__ binned, const int* __restrict__ startTab,
                            const int* __restrict__ cntTab, const int* __restrict__ bucketBase,
                            int* __restrict__ offs, int* __restrict__ csr) {
    __shared__ u32 ebuf[CAP];
    __shared__ int cbuf[CAP];
    __shared__ int runoff[B_A + 1];
    __shared__ int runstart[B_A];
    __shared__ int hist[256];
    __shared__ int cursor[256];
    __shared__ int ws[4];
    int b = blockIdx.x, t = threadIdx.x;
    int c = (t < B_A) ? cntTab[t * NBUK + b] : 0;
    int incl = blockScan256(c, ws, t);
    if (t < B_A) {
        runoff[t]   = incl - c;
        runstart[t] = t * EPB + startTab[t * NBUK + b];
    }
    if (t == B_A - 1) runoff[B_A] = incl;
    hist[t] = 0;
    __syncthreads();
    int tot = runoff[B_A];
    if (tot > CAP) tot = CAP;            // 16-sigma guard, never expected
    for (int i = t; i < tot; i += 256) { // flat gather: binary search run
        int lo = 0, hi = B_A;
        while (hi - lo > 1) {
            int mid = (lo + hi) >> 1;
            if (runoff[mid] <= i) lo = mid; else hi = mid;
        }
        ebuf[i] = binned[runstart[lo] + (i - runoff[lo])];
    }
    __syncthreads();
    for (int i = t; i < tot; i += 256)
        atomicAdd(&hist[ebuf[i] >> 16], 1);
    __syncthreads();
    int hv = hist[t];
    int hincl = blockScan256(hv, ws, t);
    int hexcl = hincl - hv;
    cursor[t] = hexcl;
    int node = (b << 8) + t;
    if (node < N_NODES) offs[node] = bucketBase[b] + hexcl;
    __syncthreads();
    for (int i = t; i < tot; i += 256) {
        u32 e = ebuf[i];
        int p = atomicAdd(&cursor[e >> 16], 1);
        cbuf[p] = (int)(e & 0xFFFFu);
    }
    __syncthreads();
    int gb = bucketBase[b];
    for (int i = t; i < tot; i += 256)   // linear flush to contiguous csr span
        csr[gb + i] = cbuf[i];
}

// ---- aggregation: out[i] = x[i] + sum_{j in N(i)} x[j]
// two nodes per wave: half-wave per node, 4 channels/lane via 8B loads
__global__ void agg_kernel(const u64* __restrict__ x, u64* __restrict__ out,
                           const int* __restrict__ offs, const int* __restrict__ csr) {
    int pair = (blockIdx.x * blockDim.x + threadIdx.x) >> 6;
    int lane = threadIdx.x & 63;
    int node = pair * 2 + (lane >> 5);
    int c    = lane & 31;
    if (node >= N_NODES) return;
    int j = offs[node], jend = offs[node + 1];
    u64 v = x[node * 32 + c];
    u32 lo = (u32)v, hi = (u32)(v >> 32);
    float a0 = bf_lo(lo), a1 = bf_hi(lo), a2 = bf_lo(hi), a3 = bf_hi(hi);
    for (; j + 8 <= jend; j += 8) {
        int s0 = csr[j],     s1 = csr[j + 1], s2 = csr[j + 2], s3 = csr[j + 3];
        int s4 = csr[j + 4], s5 = csr[j + 5], s6 = csr[j + 6], s7 = csr[j + 7];
        u64 w0 = x[s0 * 32 + c], w1 = x[s1 * 32 + c];
        u64 w2 = x[s2 * 32 + c], w3 = x[s3 * 32 + c];
        u64 w4 = x[s4 * 32 + c], w5 = x[s5 * 32 + c];
        u64 w6 = x[s6 * 32 + c], w7 = x[s7 * 32 + c];
        addbf4(w0, a0, a1, a2, a3); addbf4(w1, a0, a1, a2, a3);
        addbf4(w2, a0, a1, a2, a3); addbf4(w3, a0, a1, a2, a3);
        addbf4(w4, a0, a1, a2, a3); addbf4(w5, a0, a1, a2, a3);
        addbf4(w6, a0, a1, a2, a3); addbf4(w7, a0, a1, a2, a3);
    }
    for (; j + 4 <= jend; j += 4) {
        int s0 = csr[j], s1 = csr[j + 1], s2 = csr[j + 2], s3 = csr[j + 3];
        u64 w0 = x[s0 * 32 + c], w1 = x[s1 * 32 + c];
        u64 w2 = x[s2 * 32 + c], w3 = x[s3 * 32 + c];
        addbf4(w0, a0, a1, a2, a3); addbf4(w1, a0, a1, a2, a3);
        addbf4(w2, a0, a1, a2, a3); addbf4(w3, a0, a1, a2, a3);
    }
    for (; j < jend; j++) {
        u64 w = x[csr[j] * 32 + c];
        addbf4(w, a0, a1, a2, a3);
    }
    out[node * 32 + c] = (u64)bf_pack(a0, a1) | ((u64)bf_pack(a2, a3) << 32);
}

// ---- GEMM: C[n,128] = relu(A[n,128] @ W[128,128] + b), bf16 in/out, fp32 bias
__launch_bounds__(256)
__global__ void gemm_relu_kernel(const u16* __restrict__ A, const u16* __restrict__ Wt,
                                 const float* __restrict__ bias, u16* __restrict__ C,
                                 int n) {
    __shared__ u16 Ws[128][136];
    __shared__ u16 As[TILE_R][136];
    int t = threadIdx.x;
    {
        int r = t >> 1, p = t & 1;
        const uint4* s = (const uint4*)(Wt + r * 128 + p * 64);
        uint4* d = (uint4*)&Ws[r][p * 64];
        #pragma unroll
        for (int i = 0; i < 8; i++) d[i] = s[i];
    }
    int row0 = blockIdx.x * TILE_R;
    {
        int r = t >> 2, p = t & 3;
        int g = row0 + r;
        const uint4* s = (const uint4*)(A + (size_t)g * 128 + p * 32);
        uint4* d = (uint4*)&As[r][p * 32];
        #pragma unroll
        for (int i = 0; i < 4; i++) {
            uint4 v = make_uint4(0, 0, 0, 0);
            if (g < n) v = s[i];
            d[i] = v;
        }
    }
    __syncthreads();

    int w = t >> 6, lane = t & 63;
    int lm = lane & 15, lq = lane >> 4;
    f32x4 acc[8];
    #pragma unroll
    for (int c = 0; c < 8; c++) acc[c] = (f32x4){0.f, 0.f, 0.f, 0.f};
    #pragma unroll
    for (int kk = 0; kk < 4; kk++) {
        bf16x8 af = *(const bf16x8*)&As[w * 16 + lm][kk * 32 + lq * 8];
        #pragma unroll
        for (int c = 0; c < 8; c++) {
            bf16x8 bf = *(const bf16x8*)&Ws[c * 16 + lm][kk * 32 + lq * 8];
            acc[c] = __builtin_amdgcn_mfma_f32_16x16x32_bf16(af, bf, acc[c], 0, 0, 0);
        }
    }
    #pragma unroll
    for (int c = 0; c < 8; c++) {
        #pragma unroll
        for (int r = 0; r < 4; r++) {
            int row = row0 + w * 16 + lq * 4 + r;
            int col = c * 16 + lm;
            if (row < n) {
                float v = acc[c][r] + bias[col];
                v = v > 0.f ? v : 0.f;
                C[(size_t)row * 128 + col] = f2bf(v);
            }
        }
    }
}

// ---- final FC: out[n,2] = t2[n,128] @ Wc[128,2] + bc ; wave per node; fp32 out
__global__ void fc_kernel(const u32* __restrict__ T2, const float* __restrict__ Wc,
                          const float* __restrict__ bc, float2* __restrict__ out) {
    int wid  = (blockIdx.x * blockDim.x + threadIdx.x) >> 6;
    int lane = threadIdx.x & 63;
    if (wid >= N_NODES) return;
    u32 v = T2[wid * 64 + lane];
    float f0 = bf_lo(v), f1 = bf_hi(v);
    float4 wv = ((const float4*)Wc)[lane];
    float p0 = f0 * wv.x + f1 * wv.z;
    float p1 = f0 * wv.y + f1 * wv.w;
    #pragma unroll
    for (int off = 32; off; off >>= 1) {
        p0 += __shfl_xor(p0, off);
        p1 += __shfl_xor(p1, off);
    }
    if (lane == 0) out[wid] = make_float2(p0 + bc[0], p1 + bc[1]);
}

extern "C" void kernel_launch(void* const* d_in, const int* in_sizes, int n_in,
                              void* d_out, int out_size, void* d_ws, size_t ws_size,
                              hipStream_t stream) {
    const float* x   = (const float*)d_in[0];
    const int*   ei  = (const int*)d_in[1];
    const float* W1a = (const float*)d_in[2];
    const float* b1a = (const float*)d_in[3];
    const float* W1b = (const float*)d_in[4];
    const float* b1b = (const float*)d_in[5];
    const float* W2a = (const float*)d_in[6];
    const float* b2a = (const float*)d_in[7];
    const float* W2b = (const float*)d_in[8];
    const float* b2b = (const float*)d_in[9];
    const float* Wfc = (const float*)d_in[10];
    const float* bfc = (const float*)d_in[11];

    const int* esrc = ei;
    const int* edst = ei + N_EDGES;

    char* w = (char*)d_ws;
    size_t off = 0;
    auto alloc = [&](size_t bytes) -> char* {
        char* p = w + off;
        off = (off + bytes + 255) & ~(size_t)255;
        return p;
    };
    int*   offs     = (int*)alloc((N_NODES + 1) * 4);
    int*   startTab = (int*)alloc((size_t)B_A * NBUK * 4);
    int*   cntTab   = (int*)alloc((size_t)B_A * NBUK * 4);
    int*   bucketBase = (int*)alloc(NBUK * 4);
    int*   csr      = (int*)alloc((size_t)N_EDGES * 4);
    u16*   wt1a     = (u16*)alloc(128 * 128 * 2);
    u16*   wt1b     = (u16*)alloc(128 * 128 * 2);
    u16*   wt2a     = (u16*)alloc(128 * 128 * 2);
    float* Wc       = (float*)alloc(256 * 4);
    float* bc       = (float*)alloc(2 * 4);
    u16*   bufA     = (u16*)alloc((size_t)N_NODES * 128 * 2);
    u16*   bufB     = (u16*)alloc((size_t)N_NODES * 128 * 2);
    // binned edge staging aliases bufA: consumed by binB before agg1 writes bufA
    u32*   binned   = (u32*)bufA;

    prep_kernel<<<193, 256, 0, stream>>>(W1a, W1b, W2a, W2b, Wfc, b2b, bfc,
                                         wt1a, wt1b, wt2a, Wc, bc);
    binA_kernel<<<B_A, 256, 0, stream>>>(esrc, edst, binned, startTab, cntTab);
    bscan_kernel<<<1, 256, 0, stream>>>(cntTab, bucketBase, offs);
    binB_kernel<<<NBUK, 256, 0, stream>>>(binned, startTab, cntTab, bucketBase, offs, csr);

    const int AGG_B = (N_NODES / 2 + 3) / 4;     // pair-per-wave, 4 waves/block
    const int TILES = (N_NODES + TILE_R - 1) / TILE_R;
    const int CVT_B = (N_NODES * 64 + 255) / 256;

    // x (fp32) -> bufB (packed bf16)
    tobf16_kernel<<<CVT_B, 256, 0, stream>>>(x, (u32*)bufB, N_NODES * 64);
    // conv1: agg -> bufA ; gemm(W1a)+relu -> bufB ; gemm(W1b)+outer relu -> bufA (=h1)
    agg_kernel<<<AGG_B, 256, 0, stream>>>((const u64*)bufB, (u64*)bufA, offs, csr);
    gemm_relu_kernel<<<TILES, 256, 0, stream>>>(bufA, wt1a, b1a, bufB, N_NODES);
    gemm_relu_kernel<<<TILES, 256, 0, stream>>>(bufB, wt1b, b1b, bufA, N_NODES);
    // conv2: agg(h1) -> bufB ; gemm(W2a)+relu -> bufA (=t2)
    agg_kernel<<<AGG_B, 256, 0, stream>>>((const u64*)bufA, (u64*)bufB, offs, csr);
    gemm_relu_kernel<<<TILES, 256, 0, stream>>>(bufB, wt2a, b2a, bufA, N_NODES);
    // fc: t2 @ (W2b@Wfc) + (b2b@Wfc + bfc) -> d_out (fp32)
    fc_kernel<<<(N_NODES + 3) / 4, 256, 0, stream>>>((const u32*)bufA, Wc, bc, (float2*)d_out);
}